// Round 1
// baseline (56074.939 us; speedup 1.0000x reference)
//
#include <hip/hip_runtime.h>
#include <hip/hip_bf16.h>

#define TSZ 16

__device__ __constant__ int EDGE_A[19] = {1,8,9,1,11,12,1,2,3,2,1,5,6,5,0,0,0,14,15};
__device__ __constant__ int EDGE_B[19] = {8,9,10,11,12,13,2,3,4,16,5,6,7,17,1,14,15,16,17};

__device__ __forceinline__ float to_f(float v) { return v; }
__device__ __forceinline__ float to_f(__hip_bfloat16 v) { return __bfloat162float(v); }

// Generic fused 5x5 conv + bias + relu stage over LDS tiles.
// Input tile SIN x SIN x CIN, output tile SOUT x SOUT x COUT (SOUT = SIN - 4).
// (gy0,gx0) = global image coords of output-local (0,0); outputs outside the
// 128x128 image are forced to ZERO (matches per-layer zero padding semantics).
template<int CIN, int SIN, int SOUT, int COUT, typename TI, typename TO>
__device__ __forceinline__ void conv5x5_relu(const TI* __restrict__ sin,
                                             TO* __restrict__ sout,
                                             const float* __restrict__ w,
                                             const float* __restrict__ bias,
                                             int gy0, int gx0, int tid)
{
    constexpr int NPX = SOUT * SOUT;
#pragma unroll 1
    for (int g = 0; g < COUT; g += 4) {
        const float b0 = bias[g + 0], b1 = bias[g + 1];
        const float b2 = bias[g + 2], b3 = bias[g + 3];
#pragma unroll 1
        for (int p0 = 0; p0 < NPX; p0 += 256) {
            int p = p0 + tid;
            if (p < NPX) {
                int y = p / SOUT;
                int x = p - y * SOUT;
                bool ok = ((unsigned)(gy0 + y) < 128u) && ((unsigned)(gx0 + x) < 128u);
                float a0 = b0, a1 = b1, a2 = b2, a3 = b3;
                if (ok) {
#pragma unroll 1
                    for (int ic = 0; ic < CIN; ++ic) {
                        const TI* ib = sin + (ic * SIN + y) * SIN + x;
                        const float* wp = w + (g * CIN + ic) * 25;  // oc=g row; +CIN*25 per oc
#pragma unroll
                        for (int ky = 0; ky < 5; ++ky) {
#pragma unroll
                            for (int kx = 0; kx < 5; ++kx) {
                                float v = to_f(ib[ky * SIN + kx]);
                                int wi = ky * 5 + kx;
                                a0 = fmaf(v, wp[wi], a0);
                                a1 = fmaf(v, wp[CIN * 25 + wi], a1);
                                a2 = fmaf(v, wp[2 * CIN * 25 + wi], a2);
                                a3 = fmaf(v, wp[3 * CIN * 25 + wi], a3);
                            }
                        }
                    }
                    a0 = fmaxf(a0, 0.f); a1 = fmaxf(a1, 0.f);
                    a2 = fmaxf(a2, 0.f); a3 = fmaxf(a3, 0.f);
                } else {
                    a0 = a1 = a2 = a3 = 0.f;  // per-layer zero padding outside image
                }
                sout[(g + 0) * NPX + p] = (TO)a0;
                sout[(g + 1) * NPX + p] = (TO)a1;
                sout[(g + 2) * NPX + p] = (TO)a2;
                sout[(g + 3) * NPX + p] = (TO)a3;
            }
        }
    }
}

// One block = one 16x16 output tile of one of the 304 gathered 4-ch images.
// Full 7-layer pipeline fused in LDS; intermediates bf16 (fp32 accumulate).
extern "C" __global__ void __launch_bounds__(256)
gnn_paf_fused(const float* __restrict__ cnn,
              const float* __restrict__ w0, const float* __restrict__ b0,
              const float* __restrict__ w1, const float* __restrict__ b1,
              const float* __restrict__ w2, const float* __restrict__ b2,
              const float* __restrict__ w3, const float* __restrict__ b3,
              const float* __restrict__ w4, const float* __restrict__ b4,
              const float* __restrict__ w5, const float* __restrict__ b5,
              const float* __restrict__ w6, const float* __restrict__ b6,
              float* __restrict__ out)
{
    // LDS union, stages alternate ends; max live pair = 62464 B (< 64 KB).
    //  s_in fp32 4x36x36   @0      (20736 B)
    //  s0  bf16 16x32x32   @29696  (32768 B)
    //  s1  bf16 16x28x28   @0      (25088 B)
    //  s2  bf16 32x24x24   @25600  (36864 B)
    //  s3  bf16 32x20x20   @0      (25600 B)
    //  s4  fp32 32x16x16   @29696  (32768 B)
    __shared__ __align__(16) unsigned char smem[62464];
    float*          s_in = (float*)smem;
    __hip_bfloat16* s0   = (__hip_bfloat16*)(smem + 29696);
    __hip_bfloat16* s1   = (__hip_bfloat16*)(smem);
    __hip_bfloat16* s2   = (__hip_bfloat16*)(smem + 25600);
    __hip_bfloat16* s3   = (__hip_bfloat16*)(smem);
    float*          s4   = (float*)(smem + 29696);

    const int tid  = threadIdx.x;
    const int tile = blockIdx.x;     // 0..63
    const int img  = blockIdx.y;     // 0..303
    const int oy = (tile >> 3) * TSZ;
    const int ox = (tile & 7) * TSZ;
    const int n = img / 19;
    const int g = img - n * 19;
    const int ch0 = EDGE_A[g], ch1 = EDGE_B[g], ch2 = 19 + 2 * g, ch3 = 20 + 2 * g;

    // ---- Gather: cnn[n, CH_IDX[g], oy-10 : oy+26, ox-10 : ox+26] -> s_in (zero-pad)
    {
        const long long nb = (long long)n * 57;
        int chs[4] = {ch0, ch1, ch2, ch3};
        for (int idx = tid; idx < 4 * 36 * 36; idx += 256) {
            int c   = idx / 1296;
            int rem = idx - c * 1296;
            int r   = rem / 36;
            int col = rem - r * 36;
            int gy = oy - 10 + r, gx = ox - 10 + col;
            float v = 0.f;
            if ((unsigned)gy < 128u && (unsigned)gx < 128u)
                v = cnn[(((long long)(nb + chs[c])) * 128 + gy) * 128 + gx];
            s_in[idx] = v;
        }
    }
    __syncthreads();

    conv5x5_relu< 4, 36, 32, 16, float,          __hip_bfloat16>(s_in, s0, w0, b0, oy - 8, ox - 8, tid);
    __syncthreads();
    conv5x5_relu<16, 32, 28, 16, __hip_bfloat16, __hip_bfloat16>(s0,   s1, w1, b1, oy - 6, ox - 6, tid);
    __syncthreads();
    conv5x5_relu<16, 28, 24, 32, __hip_bfloat16, __hip_bfloat16>(s1,   s2, w2, b2, oy - 4, ox - 4, tid);
    __syncthreads();
    conv5x5_relu<32, 24, 20, 32, __hip_bfloat16, __hip_bfloat16>(s2,   s3, w3, b3, oy - 2, ox - 2, tid);
    __syncthreads();
    conv5x5_relu<32, 20, 16, 32, __hip_bfloat16, float         >(s3,   s4, w4, b4, oy,     ox,     tid);
    __syncthreads();

    // ---- conv5 (1x1, 32->128) + relu + conv6 (1x1, 128->2), fully in registers.
    {
        float xv[32];
#pragma unroll
        for (int i = 0; i < 32; ++i) xv[i] = s4[i * 256 + tid];
        float o0 = b6[0], o1 = b6[1];
#pragma unroll 1
        for (int oc = 0; oc < 128; ++oc) {
            const float* wp = w5 + oc * 32;
            float h0 = 0.f, h1 = 0.f, h2 = 0.f, h3 = 0.f;
#pragma unroll
            for (int i = 0; i < 8; ++i) {
                h0 = fmaf(xv[4 * i + 0], wp[4 * i + 0], h0);
                h1 = fmaf(xv[4 * i + 1], wp[4 * i + 1], h1);
                h2 = fmaf(xv[4 * i + 2], wp[4 * i + 2], h2);
                h3 = fmaf(xv[4 * i + 3], wp[4 * i + 3], h3);
            }
            float h = fmaxf((h0 + h1) + (h2 + h3) + b5[oc], 0.f);
            o0 = fmaf(h, w6[oc], o0);
            o1 = fmaf(h, w6[128 + oc], o1);
        }
        int y = tid >> 4, x = tid & 15;
        int gy = oy + y, gx = ox + x;
        out[(((long long)n * 38 + 2 * g + 0) * 128 + gy) * 128 + gx] = o0;
        out[(((long long)n * 38 + 2 * g + 1) * 128 + gy) * 128 + gx] = o1;
    }
}

extern "C" void kernel_launch(void* const* d_in, const int* in_sizes, int n_in,
                              void* d_out, int out_size, void* d_ws, size_t ws_size,
                              hipStream_t stream) {
    const float* cnn = (const float*)d_in[0];
    // d_in[1] = gnn_interations (unused by reference)
    const float* w0 = (const float*)d_in[2];  const float* b0 = (const float*)d_in[3];
    const float* w1 = (const float*)d_in[4];  const float* b1 = (const float*)d_in[5];
    const float* w2 = (const float*)d_in[6];  const float* b2 = (const float*)d_in[7];
    const float* w3 = (const float*)d_in[8];  const float* b3 = (const float*)d_in[9];
    const float* w4 = (const float*)d_in[10]; const float* b4 = (const float*)d_in[11];
    const float* w5 = (const float*)d_in[12]; const float* b5 = (const float*)d_in[13];
    const float* w6 = (const float*)d_in[14]; const float* b6 = (const float*)d_in[15];
    float* out = (float*)d_out;

    dim3 grid(64, 304);   // 8x8 tiles of 16x16 per image, 304 images
    dim3 block(256);
    hipLaunchKernelGGL(gnn_paf_fused, grid, block, 0, stream,
                       cnn, w0, b0, w1, b1, w2, b2, w3, b3, w4, b4, w5, b5, w6, b6, out);
}

// Round 2
// 17257.480 us; speedup vs baseline: 3.2493x; 3.2493x over previous
//
#include <hip/hip_runtime.h>

typedef __bf16  bf16x8 __attribute__((ext_vector_type(8)));
typedef float   f32x4  __attribute__((ext_vector_type(4)));

__device__ __constant__ int EDGE_A[19] = {1,8,9,1,11,12,1,2,3,2,1,5,6,5,0,0,0,14,15};
__device__ __constant__ int EDGE_B[19] = {8,9,10,11,12,13,2,3,4,16,5,6,7,17,1,14,15,16,17};

// round-to-nearest-even fp32 -> bf16 bits
__device__ __forceinline__ unsigned short f2bf(float f) {
    unsigned int x = __float_as_uint(f);
    x += 0x7FFFu + ((x >> 16) & 1u);
    return (unsigned short)(x >> 16);
}

// ---------------------------------------------------------------------------
// Weight reorder pre-pass: pack w1..w5 into MFMA-B-fragment layout, bf16, in ws.
//   W1 @0     : 13 tap-pairs x NT1 x 16n x 32k   (CIN=16 paired-taps)  6656
//   W2 @6656  : 13 x NT2 x 16 x 32                                    13312
//   W3 @19968 : 25 taps x NT2 x 16 x 32  (k=ic, CIN=32)               25600
//   W4 @45568 : 25 x NT2 x 16 x 32                                    25600
//   W5 @71168 : NT8 x 16 x 32 (1x1 conv)                               4096
// total 75264 elems = 150528 B
// ---------------------------------------------------------------------------
extern "C" __global__ void __launch_bounds__(256)
reorder_weights(const float* __restrict__ w1, const float* __restrict__ w2,
                const float* __restrict__ w3, const float* __restrict__ w4,
                const float* __restrict__ w5, unsigned short* __restrict__ ws)
{
    int idx = blockIdx.x * 256 + threadIdx.x;
    if (idx < 6656) {                       // W1: idx = tp*512 + n*32 + k
        int k = idx & 31, n = (idx >> 5) & 15, tp = idx >> 9;
        int t = 2 * tp + (k >> 4), ic = k & 15;
        float v = (t < 25) ? w1[(n * 16 + ic) * 25 + t] : 0.f;
        ws[idx] = f2bf(v);
    } else if (idx < 19968) {               // W2: j = tp*1024 + nt*512 + n*32 + k
        int j = idx - 6656;
        int k = j & 31, n = (j >> 5) & 15, nt = (j >> 9) & 1, tp = j >> 10;
        int t = 2 * tp + (k >> 4), ic = k & 15, oc = nt * 16 + n;
        float v = (t < 25) ? w2[(oc * 16 + ic) * 25 + t] : 0.f;
        ws[idx] = f2bf(v);
    } else if (idx < 45568) {               // W3
        int j = idx - 19968;
        int k = j & 31, n = (j >> 5) & 15, nt = (j >> 9) & 1, tap = j >> 10;
        int oc = nt * 16 + n;
        ws[idx] = f2bf(w3[(oc * 32 + k) * 25 + tap]);
    } else if (idx < 71168) {               // W4
        int j = idx - 45568;
        int k = j & 31, n = (j >> 5) & 15, nt = (j >> 9) & 1, tap = j >> 10;
        int oc = nt * 16 + n;
        ws[idx] = f2bf(w4[(oc * 32 + k) * 25 + tap]);
    } else if (idx < 75264) {               // W5
        int j = idx - 71168;
        int k = j & 31, oc = j >> 5;
        ws[idx] = f2bf(w5[oc * 32 + k]);
    }
}

// ---------------------------------------------------------------------------
// One 5x5 conv stage as 25 shifted GEMMs on 16x16x32 bf16 MFMA.
// sin: bf16 HWC tile [SIN*SIN][CIN]; sout: bf16 HWC [SOUT*SOUT][NT*16].
// CIN=16 packs 2 taps per MFMA (K = 2 taps x 16 ch, 13 pairs, pair 12 zero-padded
// in B). Out-of-image output pixels forced to 0 (per-layer zero padding).
// ---------------------------------------------------------------------------
template<int CIN, int SIN, int SOUT, int NT, int MAXMW>
__device__ __forceinline__ void conv_mfma(const unsigned char* __restrict__ sin,
                                          unsigned short* __restrict__ sout,
                                          const unsigned short* __restrict__ wB,
                                          const float* __restrict__ bias,
                                          int gy0, int gx0, int wave, int lane)
{
    constexpr int  NM     = (SOUT * SOUT) / 16;
    constexpr bool PAIRED = (CIN == 16);
    constexpr int  NTAP   = PAIRED ? 13 : 25;
    const int nl = lane & 15, quad = lane >> 4;

    // per-mtile A base byte offsets (lane = pixel row m of the fragment)
    int abase[MAXMW];
#pragma unroll
    for (int i = 0; i < MAXMW; ++i) {
        int mt = wave + 4 * i;
        if (mt < NM) {
            int p = mt * 16 + nl;
            int y = p / SOUT, x = p - y * SOUT;
            abase[i] = ((y * SIN + x) * CIN) * 2 + (PAIRED ? (quad & 1) * 16 : quad * 16);
        }
    }

#pragma unroll 1
    for (int nt = 0; nt < NT; ++nt) {
        f32x4 acc[MAXMW];
#pragma unroll
        for (int i = 0; i < MAXMW; ++i) acc[i] = 0.f;
        const float bval = bias[nt * 16 + nl];

        bf16x8 bfrag = *(const bf16x8*)(wB + ((0 * NT + nt) * 16 + nl) * 32 + quad * 8);
#pragma unroll 1
        for (int tp = 0; tp < NTAP; ++tp) {
            bf16x8 bnext = bfrag;
            if (tp + 1 < NTAP)
                bnext = *(const bf16x8*)(wB + (((tp + 1) * NT + nt) * 16 + nl) * 32 + quad * 8);
            int t = PAIRED ? (2 * tp + (quad >> 1)) : tp;
            if (PAIRED && t > 24) t = 24;          // pad pair; B half is zero
            int dy = t / 5, dx = t - 5 * (t / 5);
            int toff = (dy * SIN + dx) * CIN * 2;
#pragma unroll
            for (int i = 0; i < MAXMW; ++i) {
                if (wave + 4 * i < NM) {
                    bf16x8 a = *(const bf16x8*)(sin + abase[i] + toff);
                    acc[i] = __builtin_amdgcn_mfma_f32_16x16x32_bf16(a, bfrag, acc[i], 0, 0, 0);
                }
            }
            bfrag = bnext;
        }
        // epilogue: bias + relu + zero-pad mask, store bf16 HWC
#pragma unroll
        for (int i = 0; i < MAXMW; ++i) {
            int mt = wave + 4 * i;
            if (mt < NM) {
#pragma unroll
                for (int r = 0; r < 4; ++r) {
                    int p = mt * 16 + quad * 4 + r;
                    int y = p / SOUT, x = p - y * SOUT;
                    float v = fmaxf(acc[i][r] + bval, 0.f);
                    if ((unsigned)(gy0 + y) >= 128u || (unsigned)(gx0 + x) >= 128u) v = 0.f;
                    sout[p * (NT * 16) + nt * 16 + nl] = f2bf(v);
                }
            }
        }
    }
}

// ---------------------------------------------------------------------------
// Fully-fused pipeline: one block = one 16x16 output tile of one of 304 images.
// ---------------------------------------------------------------------------
extern "C" __global__ void __launch_bounds__(256)
gnn_paf_mfma(const float* __restrict__ cnn, const unsigned short* __restrict__ wB,
             const float* __restrict__ w0, const float* __restrict__ b0,
             const float* __restrict__ b1, const float* __restrict__ b2,
             const float* __restrict__ b3, const float* __restrict__ b4,
             const float* __restrict__ b5, const float* __restrict__ w6,
             const float* __restrict__ b6, float* __restrict__ out)
{
    // LDS ping-pong (byte offsets), max live pair 62464:
    //  s_in f32 [1296][4] @0 (20736) | s0 bf16 [1024][16] @29696 (32768)
    //  s1 bf16 [784][16] @0 (25088)  | s2 bf16 [576][32] @25600 (36864)
    //  s3 bf16 [400][32] @0 (25600)  | s4 bf16 [256][32] @46080 (16384)
    __shared__ __align__(16) unsigned char smem[62464];

    const int tid  = threadIdx.x;
    const int lane = tid & 63, wave = tid >> 6;
    const int tile = blockIdx.x, img = blockIdx.y;
    const int oy = (tile >> 3) * 16, ox = (tile & 7) * 16;
    const int n = img / 19, g = img - n * 19;
    const int ch0 = EDGE_A[g], ch1 = EDGE_B[g], ch2 = 19 + 2 * g, ch3 = 20 + 2 * g;

    // ---- gather -> s_in fp32 HWC4 (zero-padded 36x36 halo tile)
    {
        float4* s4p = (float4*)smem;
        const long long nb = (long long)n * 57 * 16384;
        for (int p = tid; p < 1296; p += 256) {
            int r = p / 36, col = p - r * 36;
            int gy = oy - 10 + r, gx = ox - 10 + col;
            float4 v = {0.f, 0.f, 0.f, 0.f};
            if ((unsigned)gy < 128u && (unsigned)gx < 128u) {
                int off = gy * 128 + gx;
                v.x = cnn[nb + (long long)ch0 * 16384 + off];
                v.y = cnn[nb + (long long)ch1 * 16384 + off];
                v.z = cnn[nb + (long long)ch2 * 16384 + off];
                v.w = cnn[nb + (long long)ch3 * 16384 + off];
            }
            s4p[p] = v;
        }
    }
    __syncthreads();

    // ---- conv0 (4->16, VALU, float4 LDS reads) -> s0 bf16 HWC16
    {
        const float4* sin4 = (const float4*)smem;
        unsigned int* s0w = (unsigned int*)(smem + 29696);
#pragma unroll 1
        for (int j = 0; j < 4; ++j) {
            int p = tid + 256 * j;                 // 0..1023
            int y = p >> 5, x = p & 31;
            float a[16];
#pragma unroll
            for (int oc = 0; oc < 16; ++oc) a[oc] = b0[oc];
#pragma unroll
            for (int dy = 0; dy < 5; ++dy)
#pragma unroll
                for (int dx = 0; dx < 5; ++dx) {
                    float4 v = sin4[(y + dy) * 36 + (x + dx)];
                    int t = dy * 5 + dx;
#pragma unroll
                    for (int oc = 0; oc < 16; ++oc) {
                        a[oc] = fmaf(v.x, w0[(oc * 4 + 0) * 25 + t], a[oc]);
                        a[oc] = fmaf(v.y, w0[(oc * 4 + 1) * 25 + t], a[oc]);
                        a[oc] = fmaf(v.z, w0[(oc * 4 + 2) * 25 + t], a[oc]);
                        a[oc] = fmaf(v.w, w0[(oc * 4 + 3) * 25 + t], a[oc]);
                    }
                }
            bool ok = ((unsigned)(oy - 8 + y) < 128u) && ((unsigned)(ox - 8 + x) < 128u);
#pragma unroll
            for (int oc = 0; oc < 16; oc += 2) {
                float v0 = ok ? fmaxf(a[oc], 0.f) : 0.f;
                float v1 = ok ? fmaxf(a[oc + 1], 0.f) : 0.f;
                s0w[p * 8 + (oc >> 1)] = (unsigned int)f2bf(v0) | ((unsigned int)f2bf(v1) << 16);
            }
        }
    }
    __syncthreads();

    conv_mfma<16, 32, 28, 1, 13>(smem + 29696, (unsigned short*)(smem + 0),
                                 wB + 0,     b1, oy - 6, ox - 6, wave, lane);
    __syncthreads();
    conv_mfma<16, 28, 24, 2, 9>(smem + 0,     (unsigned short*)(smem + 25600),
                                 wB + 6656,  b2, oy - 4, ox - 4, wave, lane);
    __syncthreads();
    conv_mfma<32, 24, 20, 2, 7>(smem + 25600, (unsigned short*)(smem + 0),
                                 wB + 19968, b3, oy - 2, ox - 2, wave, lane);
    __syncthreads();
    conv_mfma<32, 20, 16, 2, 4>(smem + 0,     (unsigned short*)(smem + 46080),
                                 wB + 45568, b4, oy,     ox,     wave, lane);
    __syncthreads();

    // ---- conv5 (1x1, 32->128) MFMA + relu + conv6 (128->2) quad-shuffle reduce
    {
        const unsigned char* s4b = smem + 46080;
        const unsigned short* wB5 = wB + 71168;
        const int nl = lane & 15, quad = lane >> 4;
        const float b60 = b6[0], b61 = b6[1];
#pragma unroll 1
        for (int i = 0; i < 4; ++i) {
            int mt = wave + 4 * i;                 // 0..15
            bf16x8 afrag = *(const bf16x8*)(s4b + (mt * 16 + nl) * 64 + quad * 16);
            float o0[4] = {0.f, 0.f, 0.f, 0.f}, o1[4] = {0.f, 0.f, 0.f, 0.f};
#pragma unroll 1
            for (int nt = 0; nt < 8; ++nt) {
                bf16x8 bfrag = *(const bf16x8*)(wB5 + (nt * 16 + nl) * 32 + quad * 8);
                f32x4 acc = 0.f;
                acc = __builtin_amdgcn_mfma_f32_16x16x32_bf16(afrag, bfrag, acc, 0, 0, 0);
                float bv  = b5[nt * 16 + nl];
                float w60 = w6[nt * 16 + nl];
                float w61 = w6[128 + nt * 16 + nl];
#pragma unroll
                for (int r = 0; r < 4; ++r) {
                    float h = fmaxf(acc[r] + bv, 0.f);
                    o0[r] = fmaf(h, w60, o0[r]);
                    o1[r] = fmaf(h, w61, o1[r]);
                }
            }
#pragma unroll
            for (int r = 0; r < 4; ++r) {
                float v0 = o0[r], v1 = o1[r];
#pragma unroll
                for (int m = 1; m <= 8; m <<= 1) {
                    v0 += __shfl_xor(v0, m, 64);
                    v1 += __shfl_xor(v1, m, 64);
                }
                int p = mt * 16 + quad * 4 + r;
                int y = p >> 4, x = p & 15;
                long long ob = (((long long)n * 38 + 2 * g) * 128 + (oy + y)) * 128 + (ox + x);
                if (nl == 0) out[ob]         = v0 + b60;
                if (nl == 1) out[ob + 16384] = v1 + b61;
            }
        }
    }
}

extern "C" void kernel_launch(void* const* d_in, const int* in_sizes, int n_in,
                              void* d_out, int out_size, void* d_ws, size_t ws_size,
                              hipStream_t stream) {
    const float* cnn = (const float*)d_in[0];
    const float* w0 = (const float*)d_in[2];  const float* b0 = (const float*)d_in[3];
    const float* w1 = (const float*)d_in[4];  const float* b1 = (const float*)d_in[5];
    const float* w2 = (const float*)d_in[6];  const float* b2 = (const float*)d_in[7];
    const float* w3 = (const float*)d_in[8];  const float* b3 = (const float*)d_in[9];
    const float* w4 = (const float*)d_in[10]; const float* b4 = (const float*)d_in[11];
    const float* w5 = (const float*)d_in[12]; const float* b5 = (const float*)d_in[13];
    const float* w6 = (const float*)d_in[14]; const float* b6 = (const float*)d_in[15];
    float* out = (float*)d_out;
    unsigned short* wB = (unsigned short*)d_ws;   // 150528 B used

    hipLaunchKernelGGL(reorder_weights, dim3(294), dim3(256), 0, stream,
                       w1, w2, w3, w4, w5, wB);
    hipLaunchKernelGGL(gnn_paf_mfma, dim3(64, 304), dim3(256), 0, stream,
                       cnn, wB, w0, b0, b1, b2, b3, b4, b5, w6, b6, out);
}

// Round 3
// 16433.365 us; speedup vs baseline: 3.4123x; 1.0501x over previous
//
#include <hip/hip_runtime.h>

typedef __bf16  bf16x8 __attribute__((ext_vector_type(8)));
typedef float   f32x4  __attribute__((ext_vector_type(4)));

__device__ __constant__ int EDGE_A[19] = {1,8,9,1,11,12,1,2,3,2,1,5,6,5,0,0,0,14,15};
__device__ __constant__ int EDGE_B[19] = {8,9,10,11,12,13,2,3,4,16,5,6,7,17,1,14,15,16,17};

// round-to-nearest-even fp32 -> bf16 bits
__device__ __forceinline__ unsigned short f2bf(float f) {
    unsigned int x = __float_as_uint(f);
    x += 0x7FFFu + ((x >> 16) & 1u);
    return (unsigned short)(x >> 16);
}

// ---------------------------------------------------------------------------
// Weight reorder pre-pass (identical layout to R2): MFMA-B-fragment bf16 in ws.
//   W1 @0     : 13 tap-pairs x 1nt x 16n x 32k    6656
//   W2 @6656  : 13 x 2 x 16 x 32                 13312
//   W3 @19968 : 25 taps x 2 x 16 x 32 (k=ic)     25600
//   W4 @45568 : 25 x 2 x 16 x 32                 25600
//   W5 @71168 : 8nt x 16 x 32 (1x1)               4096
// ---------------------------------------------------------------------------
extern "C" __global__ void __launch_bounds__(256)
reorder_weights(const float* __restrict__ w1, const float* __restrict__ w2,
                const float* __restrict__ w3, const float* __restrict__ w4,
                const float* __restrict__ w5, unsigned short* __restrict__ ws)
{
    int idx = blockIdx.x * 256 + threadIdx.x;
    if (idx < 6656) {
        int k = idx & 31, n = (idx >> 5) & 15, tp = idx >> 9;
        int t = 2 * tp + (k >> 4), ic = k & 15;
        float v = (t < 25) ? w1[(n * 16 + ic) * 25 + t] : 0.f;
        ws[idx] = f2bf(v);
    } else if (idx < 19968) {
        int j = idx - 6656;
        int k = j & 31, n = (j >> 5) & 15, nt = (j >> 9) & 1, tp = j >> 10;
        int t = 2 * tp + (k >> 4), ic = k & 15, oc = nt * 16 + n;
        float v = (t < 25) ? w2[(oc * 16 + ic) * 25 + t] : 0.f;
        ws[idx] = f2bf(v);
    } else if (idx < 45568) {
        int j = idx - 19968;
        int k = j & 31, n = (j >> 5) & 15, nt = (j >> 9) & 1, tap = j >> 10;
        int oc = nt * 16 + n;
        ws[idx] = f2bf(w3[(oc * 32 + k) * 25 + tap]);
    } else if (idx < 71168) {
        int j = idx - 45568;
        int k = j & 31, n = (j >> 5) & 15, nt = (j >> 9) & 1, tap = j >> 10;
        int oc = nt * 16 + n;
        ws[idx] = f2bf(w4[(oc * 32 + k) * 25 + tap]);
    } else if (idx < 75264) {
        int j = idx - 71168;
        int k = j & 31, oc = j >> 5;
        ws[idx] = f2bf(w5[oc * 32 + k]);
    }
}

// ---------------------------------------------------------------------------
// 5x5 conv stage as shifted GEMMs, 16x16x32 bf16 MFMA, 8-wave block.
// nt-fused: A read once per (mtile,tap), used by both oc-halves.
// B prefetched one tap ahead (global/L2 latency off the critical path).
// ---------------------------------------------------------------------------
template<int CIN, int SIN, int SOUT, int NT, int MAXMW>
__device__ __forceinline__ void conv_mfma(const unsigned char* __restrict__ sin,
                                          unsigned short* __restrict__ sout,
                                          const unsigned short* __restrict__ wB,
                                          const float* __restrict__ bias,
                                          int gy0, int gx0, int wave, int lane)
{
    constexpr int  NM     = (SOUT * SOUT) / 16;
    constexpr bool PAIRED = (CIN == 16);
    constexpr int  NTAP   = PAIRED ? 13 : 25;
    constexpr int  BSTR   = NT * 512;            // wB elems per tap
    const int nl = lane & 15, quad = lane >> 4;

    int abase[MAXMW];
#pragma unroll
    for (int i = 0; i < MAXMW; ++i) {
        int mt = wave + 8 * i;
        if (mt < NM) {
            int p = mt * 16 + nl;
            int y = p / SOUT, x = p - y * SOUT;
            abase[i] = ((y * SIN + x) * CIN) * 2 + (PAIRED ? (quad & 1) * 16 : quad * 16);
        }
    }

    float bv[NT];
#pragma unroll
    for (int nt = 0; nt < NT; ++nt) bv[nt] = bias[nt * 16 + nl];

    f32x4 acc[MAXMW][NT];
#pragma unroll
    for (int i = 0; i < MAXMW; ++i)
#pragma unroll
        for (int nt = 0; nt < NT; ++nt) acc[i][nt] = 0.f;

    bf16x8 bcur[NT], bnxt[NT];
#pragma unroll
    for (int nt = 0; nt < NT; ++nt)
        bcur[nt] = *(const bf16x8*)(wB + (nt * 16 + nl) * 32 + quad * 8);

#pragma unroll 1
    for (int tp = 0; tp < NTAP; ++tp) {
        if (tp + 1 < NTAP) {
#pragma unroll
            for (int nt = 0; nt < NT; ++nt)
                bnxt[nt] = *(const bf16x8*)(wB + (tp + 1) * BSTR + (nt * 16 + nl) * 32 + quad * 8);
        }
        int t = PAIRED ? (2 * tp + (quad >> 1)) : tp;
        if (PAIRED && t > 24) t = 24;            // pad tap; its B half is zero
        int dy = t / 5, dx = t - 5 * dy;
        int toff = (dy * SIN + dx) * CIN * 2;
#pragma unroll
        for (int i = 0; i < MAXMW; ++i) {
            if (wave + 8 * i < NM) {
                bf16x8 a = *(const bf16x8*)(sin + abase[i] + toff);
#pragma unroll
                for (int nt = 0; nt < NT; ++nt)
                    acc[i][nt] = __builtin_amdgcn_mfma_f32_16x16x32_bf16(a, bcur[nt], acc[i][nt], 0, 0, 0);
            }
        }
#pragma unroll
        for (int nt = 0; nt < NT; ++nt) bcur[nt] = bnxt[nt];
    }

#pragma unroll
    for (int i = 0; i < MAXMW; ++i) {
        int mt = wave + 8 * i;
        if (mt < NM) {
#pragma unroll
            for (int r = 0; r < 4; ++r) {
                int p = mt * 16 + quad * 4 + r;
                int y = p / SOUT, x = p - y * SOUT;
                bool oob = ((unsigned)(gy0 + y) >= 128u) || ((unsigned)(gx0 + x) >= 128u);
#pragma unroll
                for (int nt = 0; nt < NT; ++nt) {
                    float v = fmaxf(acc[i][nt][r] + bv[nt], 0.f);
                    if (oob) v = 0.f;
                    sout[p * (NT * 16) + nt * 16 + nl] = f2bf(v);
                }
            }
        }
    }
}

// ---------------------------------------------------------------------------
// Fused pipeline: one 512-thread block = one 16x16 output tile of 304 images.
// ---------------------------------------------------------------------------
extern "C" __global__ void __launch_bounds__(512, 4)
gnn_paf_mfma(const float* __restrict__ cnn, const unsigned short* __restrict__ wB,
             const float* __restrict__ w0, const float* __restrict__ b0,
             const float* __restrict__ b1, const float* __restrict__ b2,
             const float* __restrict__ b3, const float* __restrict__ b4,
             const float* __restrict__ b5, const float* __restrict__ w6,
             const float* __restrict__ b6, float* __restrict__ out)
{
    //  s_in f32 [1296][4] @0 (20736) | s0 bf16 [1024][16] @29696 (32768)
    //  s1 bf16 [784][16] @0 (25088)  | s2 bf16 [576][32] @25600 (36864)
    //  s3 bf16 [400][32] @0 (25600)  | s4 bf16 [256][32] @46080 (16384)
    __shared__ __align__(16) unsigned char smem[62464];

    const int tid  = threadIdx.x;
    const int lane = tid & 63, wave = tid >> 6;       // 8 waves
    const int tile = blockIdx.x, img = blockIdx.y;
    const int oy = (tile >> 3) * 16, ox = (tile & 7) * 16;
    const int n = img / 19, g = img - n * 19;
    const int ch0 = EDGE_A[g], ch1 = EDGE_B[g], ch2 = 19 + 2 * g, ch3 = 20 + 2 * g;

    // ---- gather -> s_in fp32 HWC4 (zero-padded 36x36 halo)
    {
        float4* s4p = (float4*)smem;
        const long long nb = (long long)n * 57 * 16384;
        for (int p = tid; p < 1296; p += 512) {
            int r = p / 36, col = p - r * 36;
            int gy = oy - 10 + r, gx = ox - 10 + col;
            float4 v = {0.f, 0.f, 0.f, 0.f};
            if ((unsigned)gy < 128u && (unsigned)gx < 128u) {
                int off = gy * 128 + gx;
                v.x = cnn[nb + (long long)ch0 * 16384 + off];
                v.y = cnn[nb + (long long)ch1 * 16384 + off];
                v.z = cnn[nb + (long long)ch2 * 16384 + off];
                v.w = cnn[nb + (long long)ch3 * 16384 + off];
            }
            s4p[p] = v;
        }
    }
    __syncthreads();

    // ---- conv0 (4->16, VALU) -> s0 bf16 HWC16
    {
        const float4* sin4 = (const float4*)smem;
        unsigned int* s0w = (unsigned int*)(smem + 29696);
#pragma unroll 1
        for (int j = 0; j < 2; ++j) {
            int p = tid + 512 * j;                 // 0..1023
            int y = p >> 5, x = p & 31;
            float a[16];
#pragma unroll
            for (int oc = 0; oc < 16; ++oc) a[oc] = b0[oc];
#pragma unroll
            for (int dy = 0; dy < 5; ++dy)
#pragma unroll
                for (int dx = 0; dx < 5; ++dx) {
                    float4 v = sin4[(y + dy) * 36 + (x + dx)];
                    int t = dy * 5 + dx;
#pragma unroll
                    for (int oc = 0; oc < 16; ++oc) {
                        a[oc] = fmaf(v.x, w0[(oc * 4 + 0) * 25 + t], a[oc]);
                        a[oc] = fmaf(v.y, w0[(oc * 4 + 1) * 25 + t], a[oc]);
                        a[oc] = fmaf(v.z, w0[(oc * 4 + 2) * 25 + t], a[oc]);
                        a[oc] = fmaf(v.w, w0[(oc * 4 + 3) * 25 + t], a[oc]);
                    }
                }
            bool ok = ((unsigned)(oy - 8 + y) < 128u) && ((unsigned)(ox - 8 + x) < 128u);
#pragma unroll
            for (int oc = 0; oc < 16; oc += 2) {
                float v0 = ok ? fmaxf(a[oc], 0.f) : 0.f;
                float v1 = ok ? fmaxf(a[oc + 1], 0.f) : 0.f;
                s0w[p * 8 + (oc >> 1)] = (unsigned int)f2bf(v0) | ((unsigned int)f2bf(v1) << 16);
            }
        }
    }
    __syncthreads();

    conv_mfma<16, 32, 28, 1, 7>(smem + 29696, (unsigned short*)(smem + 0),
                                wB + 0,     b1, oy - 6, ox - 6, wave, lane);
    __syncthreads();
    conv_mfma<16, 28, 24, 2, 5>(smem + 0,     (unsigned short*)(smem + 25600),
                                wB + 6656,  b2, oy - 4, ox - 4, wave, lane);
    __syncthreads();
    conv_mfma<32, 24, 20, 2, 4>(smem + 25600, (unsigned short*)(smem + 0),
                                wB + 19968, b3, oy - 2, ox - 2, wave, lane);
    __syncthreads();
    conv_mfma<32, 20, 16, 2, 2>(smem + 0,     (unsigned short*)(smem + 46080),
                                wB + 45568, b4, oy,     ox,     wave, lane);
    __syncthreads();

    // ---- conv5 (1x1, 32->128) MFMA + relu + conv6 (128->2); zero global loads in loop
    {
        const unsigned char* s4b = smem + 46080;
        const unsigned short* wB5 = wB + 71168;
        const int nl = lane & 15, quad = lane >> 4;
        float bv[8], w60v[8], w61v[8];
        bf16x8 bf[8];
#pragma unroll
        for (int nt = 0; nt < 8; ++nt) {
            bv[nt]   = b5[nt * 16 + nl];
            w60v[nt] = w6[nt * 16 + nl];
            w61v[nt] = w6[128 + nt * 16 + nl];
            bf[nt]   = *(const bf16x8*)(wB5 + (nt * 16 + nl) * 32 + quad * 8);
        }
        const float b60 = b6[0], b61 = b6[1];
#pragma unroll 1
        for (int i = 0; i < 2; ++i) {
            int mt = wave + 8 * i;                 // 0..15
            bf16x8 afrag = *(const bf16x8*)(s4b + (mt * 16 + nl) * 64 + quad * 16);
            float o0[4] = {0.f, 0.f, 0.f, 0.f}, o1[4] = {0.f, 0.f, 0.f, 0.f};
#pragma unroll
            for (int nt = 0; nt < 8; ++nt) {
                f32x4 acc = 0.f;
                acc = __builtin_amdgcn_mfma_f32_16x16x32_bf16(afrag, bf[nt], acc, 0, 0, 0);
#pragma unroll
                for (int r = 0; r < 4; ++r) {
                    float h = fmaxf(acc[r] + bv[nt], 0.f);
                    o0[r] = fmaf(h, w60v[nt], o0[r]);
                    o1[r] = fmaf(h, w61v[nt], o1[r]);
                }
            }
#pragma unroll
            for (int r = 0; r < 4; ++r) {
                float v0 = o0[r], v1 = o1[r];
#pragma unroll
                for (int m = 1; m <= 8; m <<= 1) {
                    v0 += __shfl_xor(v0, m, 64);
                    v1 += __shfl_xor(v1, m, 64);
                }
                int p = mt * 16 + quad * 4 + r;
                int y = p >> 4, x = p & 15;
                long long ob = (((long long)n * 38 + 2 * g) * 128 + (oy + y)) * 128 + (ox + x);
                if (nl == 0) out[ob]         = v0 + b60;
                if (nl == 1) out[ob + 16384] = v1 + b61;
            }
        }
    }
}

extern "C" void kernel_launch(void* const* d_in, const int* in_sizes, int n_in,
                              void* d_out, int out_size, void* d_ws, size_t ws_size,
                              hipStream_t stream) {
    const float* cnn = (const float*)d_in[0];
    const float* w0 = (const float*)d_in[2];  const float* b0 = (const float*)d_in[3];
    const float* w1 = (const float*)d_in[4];  const float* b1 = (const float*)d_in[5];
    const float* w2 = (const float*)d_in[6];  const float* b2 = (const float*)d_in[7];
    const float* w3 = (const float*)d_in[8];  const float* b3 = (const float*)d_in[9];
    const float* w4 = (const float*)d_in[10]; const float* b4 = (const float*)d_in[11];
    const float* w5 = (const float*)d_in[12]; const float* b5 = (const float*)d_in[13];
    const float* w6 = (const float*)d_in[14]; const float* b6 = (const float*)d_in[15];
    float* out = (float*)d_out;
    unsigned short* wB = (unsigned short*)d_ws;   // 150528 B used

    hipLaunchKernelGGL(reorder_weights, dim3(294), dim3(256), 0, stream,
                       w1, w2, w3, w4, w5, wB);
    hipLaunchKernelGGL(gnn_paf_mfma, dim3(64, 304), dim3(512), 0, stream,
                       cnn, wB, w0, b0, b1, b2, b3, b4, b5, w6, b6, out);
}

// Round 4
// 1606.955 us; speedup vs baseline: 34.8952x; 10.2264x over previous
//
#include <hip/hip_runtime.h>

typedef __bf16  bf16x8 __attribute__((ext_vector_type(8)));
typedef float   f32x4  __attribute__((ext_vector_type(4)));

__device__ __constant__ int EDGE_A[19] = {1,8,9,1,11,12,1,2,3,2,1,5,6,5,0,0,0,14,15};
__device__ __constant__ int EDGE_B[19] = {8,9,10,11,12,13,2,3,4,16,5,6,7,17,1,14,15,16,17};

__device__ __forceinline__ unsigned short f2bf(float f) {
    unsigned int x = __float_as_uint(f);
    x += 0x7FFFu + ((x >> 16) & 1u);
    return (unsigned short)(x >> 16);
}

// ---------------------------------------------------------------------------
// Weight pre-pass -> A-fragment layout (lane m=oc=idx&15 holds k=quad*8+j).
//   W1 @0     : 13 tap-pairs x 1 x 16 x 32   6656   (k = h*16+ic, t=2tp+h)
//   W2 @6656  : 13 x 2 x 16 x 32            13312
//   W3 @19968 : 25 taps x 2 x 16 x 32       25600   (k = ic)
//   W4 @45568 : 25 x 2 x 16 x 32            25600
//   W5 @71168 : 8 x 16 x 32                  4096
//   W0 @75264 : 4 chunks x 16 x 32           2048   (k = tl*4+ic, t=c*8+tl)
// ---------------------------------------------------------------------------
extern "C" __global__ void __launch_bounds__(256)
reorder_weights(const float* __restrict__ w0, const float* __restrict__ w1,
                const float* __restrict__ w2, const float* __restrict__ w3,
                const float* __restrict__ w4, const float* __restrict__ w5,
                unsigned short* __restrict__ ws)
{
    int idx = blockIdx.x * 256 + threadIdx.x;
    if (idx < 6656) {
        int k = idx & 31, n = (idx >> 5) & 15, tp = idx >> 9;
        int t = 2 * tp + (k >> 4), ic = k & 15;
        float v = (t < 25) ? w1[(n * 16 + ic) * 25 + t] : 0.f;
        ws[idx] = f2bf(v);
    } else if (idx < 19968) {
        int j = idx - 6656;
        int k = j & 31, n = (j >> 5) & 15, nt = (j >> 9) & 1, tp = j >> 10;
        int t = 2 * tp + (k >> 4), ic = k & 15, oc = nt * 16 + n;
        float v = (t < 25) ? w2[(oc * 16 + ic) * 25 + t] : 0.f;
        ws[idx] = f2bf(v);
    } else if (idx < 45568) {
        int j = idx - 19968;
        int k = j & 31, n = (j >> 5) & 15, nt = (j >> 9) & 1, tap = j >> 10;
        ws[idx] = f2bf(w3[((nt * 16 + n) * 32 + k) * 25 + tap]);
    } else if (idx < 71168) {
        int j = idx - 45568;
        int k = j & 31, n = (j >> 5) & 15, nt = (j >> 9) & 1, tap = j >> 10;
        ws[idx] = f2bf(w4[((nt * 16 + n) * 32 + k) * 25 + tap]);
    } else if (idx < 75264) {
        int j = idx - 71168;
        int k = j & 31, oc = j >> 5;
        ws[idx] = f2bf(w5[oc * 32 + k]);
    } else if (idx < 77312) {
        int j = idx - 75264;
        int k = j & 31, n = (j >> 5) & 15, c = j >> 9;
        int t = c * 8 + (k >> 2), ic = k & 3;
        float v = (t < 25) ? w0[(n * 4 + ic) * 25 + t] : 0.f;
        ws[idx] = f2bf(v);
    }
}

__device__ __forceinline__ ushort4 pack_relu4(f32x4 a, float4 b, bool oob) {
    ushort4 us;
    us.x = oob ? 0 : f2bf(fmaxf(a[0] + b.x, 0.f));
    us.y = oob ? 0 : f2bf(fmaxf(a[1] + b.y, 0.f));
    us.z = oob ? 0 : f2bf(fmaxf(a[2] + b.z, 0.f));
    us.w = oob ? 0 : f2bf(fmaxf(a[3] + b.w, 0.f));
    return us;
}

// ---------------------------------------------------------------------------
// Paired-tap 5x5 stage (CIN=16): A=weights (VGPR-resident per chunk), B=pixels.
// D[m=oc][n=pixel] -> lane writes 4 contiguous oc as one b64.
// ---------------------------------------------------------------------------
template<int SIN, int SOUT, int NT, int MAXM, bool GUARD>
__device__ __forceinline__ void conv_paired(
    const unsigned short* __restrict__ sin, unsigned short* __restrict__ sout,
    const unsigned short* __restrict__ wA, const float* __restrict__ bias,
    int gy0, int gx0, int wave, int lane)
{
    constexpr int NM = (SOUT * SOUT) / 16;
    constexpr int WN = (NT == 2) ? 4 : 8;
    constexpr int TSTR = NT * 512;
    const int nl = lane & 15, quad = lane >> 4;
    const int h = quad >> 1;
    const int coff = (quad & 1) * 8;
    const int nt   = (NT == 2) ? (wave & 1) : 0;
    const int wset = (NT == 2) ? (wave >> 1) : wave;

    int abase[MAXM];
#pragma unroll
    for (int i = 0; i < MAXM; ++i) {
        int mt = wset + WN * i;
        if (!GUARD || mt < NM) {
            int p = mt * 16 + nl;
            int y = p / SOUT, x = p - y * SOUT;
            abase[i] = (y * SIN + x) * 16 + coff;
        }
    }
    f32x4 acc[MAXM];
#pragma unroll
    for (int i = 0; i < MAXM; ++i) acc[i] = (f32x4)0.f;

    const unsigned short* wp = wA + nt * 512 + nl * 32 + quad * 8;

    bf16x8 wf[7];
#pragma unroll
    for (int tp = 0; tp < 7; ++tp) wf[tp] = *(const bf16x8*)(wp + tp * TSTR);
#pragma unroll
    for (int tp = 0; tp < 7; ++tp) {
        int t = 2 * tp + h;
        int dy = t / 5, dx = t - 5 * dy;
        int toff = (dy * SIN + dx) * 16;
#pragma unroll
        for (int i = 0; i < MAXM; ++i)
            if (!GUARD || wset + WN * i < NM) {
                bf16x8 a = *(const bf16x8*)(sin + abase[i] + toff);
                acc[i] = __builtin_amdgcn_mfma_f32_16x16x32_bf16(wf[tp], a, acc[i], 0, 0, 0);
            }
    }
#pragma unroll
    for (int tp = 0; tp < 6; ++tp) wf[tp] = *(const bf16x8*)(wp + (7 + tp) * TSTR);
#pragma unroll
    for (int tp = 0; tp < 6; ++tp) {
        int t = 14 + 2 * tp + h;
        if (t > 24) t = 24;                 // padded half; weights are zero
        int dy = t / 5, dx = t - 5 * dy;
        int toff = (dy * SIN + dx) * 16;
#pragma unroll
        for (int i = 0; i < MAXM; ++i)
            if (!GUARD || wset + WN * i < NM) {
                bf16x8 a = *(const bf16x8*)(sin + abase[i] + toff);
                acc[i] = __builtin_amdgcn_mfma_f32_16x16x32_bf16(wf[tp], a, acc[i], 0, 0, 0);
            }
    }

    float4 bb = *(const float4*)(bias + nt * 16 + quad * 4);
#pragma unroll
    for (int i = 0; i < MAXM; ++i) {
        int mt = wset + WN * i;
        if (!GUARD || mt < NM) {
            int p = mt * 16 + nl;
            int y = p / SOUT, x = p - y * SOUT;
            bool oob = ((unsigned)(gy0 + y) >= 128u) || ((unsigned)(gx0 + x) >= 128u);
            *(ushort4*)(sout + p * (NT * 16) + nt * 16 + quad * 4) = pack_relu4(acc[i], bb, oob);
        }
    }
}

// ---------------------------------------------------------------------------
// CIN=32 5x5 stage (k=ic), NT=2. Tap chunks 9/8/8 -> weights <=36 VGPR.
// ---------------------------------------------------------------------------
template<int SIN, int SOUT, int MAXM, bool GUARD>
__device__ __forceinline__ void conv_c32(
    const unsigned short* __restrict__ sin, unsigned short* __restrict__ sout,
    const unsigned short* __restrict__ wA, const float* __restrict__ bias,
    int gy0, int gx0, int wave, int lane)
{
    constexpr int NM = (SOUT * SOUT) / 16;
    const int nl = lane & 15, quad = lane >> 4;
    const int nt = wave & 1, wset = wave >> 1;

    int abase[MAXM];
#pragma unroll
    for (int i = 0; i < MAXM; ++i) {
        int mt = wset + 4 * i;
        if (!GUARD || mt < NM) {
            int p = mt * 16 + nl;
            int y = p / SOUT, x = p - y * SOUT;
            abase[i] = (y * SIN + x) * 32 + quad * 8;
        }
    }
    f32x4 acc[MAXM];
#pragma unroll
    for (int i = 0; i < MAXM; ++i) acc[i] = (f32x4)0.f;

    const unsigned short* wp = wA + nt * 512 + nl * 32 + quad * 8;

    bf16x8 wf[9];
#pragma unroll
    for (int c = 0; c < 3; ++c) {
        const int t0 = (c == 0) ? 0 : (c == 1) ? 9 : 17;
        const int tn = (c == 0) ? 9 : 8;
#pragma unroll
        for (int tp = 0; tp < 9; ++tp)
            if (tp < tn) wf[tp] = *(const bf16x8*)(wp + (t0 + tp) * 1024);
#pragma unroll
        for (int tp = 0; tp < 9; ++tp) {
            if (tp < tn) {
                int t = t0 + tp;
                int dy = t / 5, dx = t - 5 * dy;
                int toff = (dy * SIN + dx) * 32;
#pragma unroll
                for (int i = 0; i < MAXM; ++i)
                    if (!GUARD || wset + 4 * i < NM) {
                        bf16x8 a = *(const bf16x8*)(sin + abase[i] + toff);
                        acc[i] = __builtin_amdgcn_mfma_f32_16x16x32_bf16(wf[tp], a, acc[i], 0, 0, 0);
                    }
            }
        }
    }

    float4 bb = *(const float4*)(bias + nt * 16 + quad * 4);
#pragma unroll
    for (int i = 0; i < MAXM; ++i) {
        int mt = wset + 4 * i;
        if (!GUARD || mt < NM) {
            int p = mt * 16 + nl;
            int y = p / SOUT, x = p - y * SOUT;
            bool oob = ((unsigned)(gy0 + y) >= 128u) || ((unsigned)(gx0 + x) >= 128u);
            *(ushort4*)(sout + p * 32 + nt * 16 + quad * 4) = pack_relu4(acc[i], bb, oob);
        }
    }
}

// ---------------------------------------------------------------------------
// Fused pipeline: one 512-thread block = one 16x16 output tile.
// LDS (65536 B): s_in@0 10368 | s0@32768 32768 | s1@0 25088 | s2@28672 36864
//                | s3@0 25600 | s4@49152 16384   (ping-pong, no overlaps)
// ---------------------------------------------------------------------------
extern "C" __global__ void __launch_bounds__(512, 4)
gnn_paf_mfma(const float* __restrict__ cnn, const unsigned short* __restrict__ wB,
             const float* __restrict__ b0, const float* __restrict__ b1,
             const float* __restrict__ b2, const float* __restrict__ b3,
             const float* __restrict__ b4, const float* __restrict__ b5,
             const float* __restrict__ w6, const float* __restrict__ b6,
             float* __restrict__ out)
{
    __shared__ __align__(16) unsigned char smem[65536];
    unsigned short* s_in = (unsigned short*)(smem);
    unsigned short* s0   = (unsigned short*)(smem + 32768);
    unsigned short* s1   = (unsigned short*)(smem);
    unsigned short* s2   = (unsigned short*)(smem + 28672);
    unsigned short* s3   = (unsigned short*)(smem);
    unsigned short* s4   = (unsigned short*)(smem + 49152);

    const int tid  = threadIdx.x;
    const int lane = tid & 63, wave = tid >> 6;
    const int tile = blockIdx.x, img = blockIdx.y;
    const int oy = (tile >> 3) * 16, ox = (tile & 7) * 16;
    const int n = img / 19, g = img - n * 19;
    const int ch0 = EDGE_A[g], ch1 = EDGE_B[g], ch2 = 19 + 2 * g, ch3 = 20 + 2 * g;
    const int nl = lane & 15, quad = lane >> 4;

    // ---- gather -> s_in bf16 HWC4 (36x36 halo, zero-padded)
    {
        const long long nb = (long long)n * 57 * 16384;
        for (int p = tid; p < 1296; p += 512) {
            int r = p / 36, col = p - r * 36;
            int gy = oy - 10 + r, gx = ox - 10 + col;
            ushort4 v = {0, 0, 0, 0};
            if ((unsigned)gy < 128u && (unsigned)gx < 128u) {
                int off = gy * 128 + gx;
                v.x = f2bf(cnn[nb + (long long)ch0 * 16384 + off]);
                v.y = f2bf(cnn[nb + (long long)ch1 * 16384 + off]);
                v.z = f2bf(cnn[nb + (long long)ch2 * 16384 + off]);
                v.w = f2bf(cnn[nb + (long long)ch3 * 16384 + off]);
            }
            *(ushort4*)(s_in + p * 4) = v;
        }
    }
    __syncthreads();

    // ---- conv0 (4->16) MFMA: K=32 = 8 taps x 4 ch, 4 chunks
    {
        bf16x8 wf[4];
#pragma unroll
        for (int c = 0; c < 4; ++c)
            wf[c] = *(const bf16x8*)(wB + 75264 + c * 512 + nl * 32 + quad * 8);
        float4 bb = *(const float4*)(b0 + quad * 4);
#pragma unroll 1
        for (int i = 0; i < 8; ++i) {
            int mt = wave + 8 * i;                 // 64 mtiles
            int p = mt * 16 + nl;
            int y = p >> 5, x = p & 31;
            f32x4 acc = (f32x4)0.f;
#pragma unroll
            for (int c = 0; c < 4; ++c) {
                int t0 = c * 8 + quad * 2, t1 = t0 + 1;
                if (t0 > 24) t0 = 24;
                if (t1 > 24) t1 = 24;              // padded taps; weights zero
                int dy0 = t0 / 5, dx0 = t0 - 5 * dy0;
                int dy1 = t1 / 5, dx1 = t1 - 5 * dy1;
                uint2 lo = *(const uint2*)(s_in + ((y + dy0) * 36 + x + dx0) * 4);
                uint2 hi = *(const uint2*)(s_in + ((y + dy1) * 36 + x + dx1) * 4);
                bf16x8 a;
                ((uint2*)&a)[0] = lo;
                ((uint2*)&a)[1] = hi;
                acc = __builtin_amdgcn_mfma_f32_16x16x32_bf16(wf[c], a, acc, 0, 0, 0);
            }
            bool oob = ((unsigned)(oy - 8 + y) >= 128u) || ((unsigned)(ox - 8 + x) >= 128u);
            *(ushort4*)(s0 + p * 16 + quad * 4) = pack_relu4(acc, bb, oob);
        }
    }
    __syncthreads();

    conv_paired<32, 28, 1, 7, true >(s0, s1, wB + 0,     b1, oy - 6, ox - 6, wave, lane);
    __syncthreads();
    conv_paired<28, 24, 2, 9, false>(s1, s2, wB + 6656,  b2, oy - 4, ox - 4, wave, lane);
    __syncthreads();
    conv_c32   <24, 20, 7, true >(s2, s3, wB + 19968, b3, oy - 2, ox - 2, wave, lane);
    __syncthreads();
    conv_c32   <20, 16, 4, false>(s3, s4, wB + 45568, b4, oy,     ox,     wave, lane);
    __syncthreads();

    // ---- conv5 (1x1 32->128) + relu + conv6 (128->2), weights VGPR-resident
    {
        bf16x8 w5f[8];
#pragma unroll
        for (int nt = 0; nt < 8; ++nt)
            w5f[nt] = *(const bf16x8*)(wB + 71168 + nt * 512 + nl * 32 + quad * 8);
        const float b6q = b6[quad & 1];
#pragma unroll 1
        for (int ii = 0; ii < 2; ++ii) {
            int mt = wave + 8 * ii;                // 16 mtiles
            bf16x8 pf = *(const bf16x8*)(s4 + mt * 512 + nl * 32 + quad * 8);
            float o0 = 0.f, o1 = 0.f;
#pragma unroll
            for (int nt = 0; nt < 8; ++nt) {
                f32x4 acc = (f32x4)0.f;
                acc = __builtin_amdgcn_mfma_f32_16x16x32_bf16(w5f[nt], pf, acc, 0, 0, 0);
                float4 bb  = *(const float4*)(b5 + nt * 16 + quad * 4);
                float4 wa  = *(const float4*)(w6 + nt * 16 + quad * 4);
                float4 wb2 = *(const float4*)(w6 + 128 + nt * 16 + quad * 4);
                float h0 = fmaxf(acc[0] + bb.x, 0.f), h1 = fmaxf(acc[1] + bb.y, 0.f);
                float h2 = fmaxf(acc[2] + bb.z, 0.f), h3 = fmaxf(acc[3] + bb.w, 0.f);
                o0 = fmaf(h0, wa.x, fmaf(h1, wa.y, fmaf(h2, wa.z, fmaf(h3, wa.w, o0))));
                o1 = fmaf(h0, wb2.x, fmaf(h1, wb2.y, fmaf(h2, wb2.z, fmaf(h3, wb2.w, o1))));
            }
            o0 += __shfl_xor(o0, 16, 64); o0 += __shfl_xor(o0, 32, 64);
            o1 += __shfl_xor(o1, 16, 64); o1 += __shfl_xor(o1, 32, 64);
            if (quad < 2) {
                float val = ((quad == 0) ? o0 : o1) + b6q;
                long long ob = (((long long)n * 38 + 2 * g + quad) * 128 + (oy + mt)) * 128 + (ox + nl);
                out[ob] = val;
            }
        }
    }
}

extern "C" void kernel_launch(void* const* d_in, const int* in_sizes, int n_in,
                              void* d_out, int out_size, void* d_ws, size_t ws_size,
                              hipStream_t stream) {
    const float* cnn = (const float*)d_in[0];
    const float* w0 = (const float*)d_in[2];  const float* b0 = (const float*)d_in[3];
    const float* w1 = (const float*)d_in[4];  const float* b1 = (const float*)d_in[5];
    const float* w2 = (const float*)d_in[6];  const float* b2 = (const float*)d_in[7];
    const float* w3 = (const float*)d_in[8];  const float* b3 = (const float*)d_in[9];
    const float* w4 = (const float*)d_in[10]; const float* b4 = (const float*)d_in[11];
    const float* w5 = (const float*)d_in[12]; const float* b5 = (const float*)d_in[13];
    const float* w6 = (const float*)d_in[14]; const float* b6 = (const float*)d_in[15];
    float* out = (float*)d_out;
    unsigned short* wB = (unsigned short*)d_ws;   // 154,624 B used

    hipLaunchKernelGGL(reorder_weights, dim3(302), dim3(256), 0, stream,
                       w0, w1, w2, w3, w4, w5, wB);
    hipLaunchKernelGGL(gnn_paf_mfma, dim3(64, 304), dim3(512), 0, stream,
                       cnn, wB, b0, b1, b2, b3, b4, b5, w6, b6, out);
}